// Round 11
// baseline (361.829 us; speedup 1.0000x reference)
//
#include <hip/hip_runtime.h>
#include <cstdint>
#include <cstddef>

#define PAD 64

// ---------- prep: build W + pad pos->float4 + zero cursor (one launch) ----------
// W [128][512]: cols 0..127 = w1_0 rows 0..127 | 128..255 = w2_0 rows 0..127
//             | 256..383 = w1_0 rows 128..255 | 384..511 = w2_0 rows 128..255
__global__ void prep_kernel(const float* __restrict__ w1_0,
                            const float* __restrict__ w2_0,
                            float* __restrict__ W,
                            const float* __restrict__ pos,
                            float4* __restrict__ pos4,
                            int* __restrict__ cursor, int N) {
    int idx = blockIdx.x * blockDim.x + threadIdx.x;
    if (idx < 128 * 512) {
        int k = idx >> 9;
        int j = idx & 511;
        float v;
        if (j < 128)      v = w1_0[k * 128 + j];
        else if (j < 256) v = w2_0[k * 128 + (j - 128)];
        else if (j < 384) v = w1_0[(128 + k) * 128 + (j - 256)];
        else              v = w2_0[(128 + k) * 128 + (j - 384)];
        W[idx] = v;
    }
    if (idx < N) {
        pos4[idx] = make_float4(pos[3 * idx + 0], pos[3 * idx + 1], pos[3 * idx + 2], 0.f);
        cursor[idx] = 0;
    }
}

// ---------- single-pass bucket scatter ----------
__global__ void bucket_kernel(const int* __restrict__ eidx,
                              int* __restrict__ cursor,
                              int* __restrict__ bucket, int E) {
    int e = blockIdx.x * blockDim.x + threadIdx.x;
    if (e >= E) return;
    int s = eidx[e];
    int d = eidx[E + e];
    int r = atomicAdd(&cursor[s], 1);
    if (r < PAD) bucket[(size_t)s * PAD + r] = d;   // P(overflow) ~ 1e-18
}

// ---------- kernel 2: GEMM  C[M,512] = X[M,128](f32) @ W[128,512](f32) ----------
// 128x128 tile, 8x8/thread (4+4 split, 64-apart), BK=32, pitch 132 (16B-aligned
// b128 for all k; fragments within 64 consecutive floats -> 2-way = free).
#define GP 132
__global__ __launch_bounds__(256) void gemm_precompute(
    const float* __restrict__ X, const float* __restrict__ W,
    float* __restrict__ SRC, float* __restrict__ DST, int M)
{
    __shared__ float sXT[32][GP];   // [k][row]
    __shared__ float sW[32][GP];    // [k][col]

    const int tid = threadIdx.x;
    const int bm = blockIdx.x * 128;
    const int bn = blockIdx.y * 128;
    const int ty = tid >> 4;
    const int tx = tid & 15;

    const int xr = tid >> 3;
    const int xc = (tid & 7) * 4;
    const int wr = tid >> 5;
    const int wc = (tid & 31) * 4;

    float acc[8][8];
#pragma unroll
    for (int i = 0; i < 8; ++i)
#pragma unroll
        for (int j = 0; j < 8; ++j) acc[i][j] = 0.f;

    for (int kt = 0; kt < 128; kt += 32) {
#pragma unroll
        for (int q = 0; q < 4; ++q) {
            int row = xr + 32 * q;
            int gr = bm + row;
            float4 v = make_float4(0.f, 0.f, 0.f, 0.f);
            if (gr < M) v = *(const float4*)(X + (size_t)gr * 128 + kt + xc);
            sXT[xc + 0][row] = v.x;
            sXT[xc + 1][row] = v.y;
            sXT[xc + 2][row] = v.z;
            sXT[xc + 3][row] = v.w;
        }
#pragma unroll
        for (int q = 0; q < 4; ++q) {
            int row = wr + 8 * q;
            float4 v = *(const float4*)(W + (size_t)(kt + row) * 512 + bn + wc);
            *(float4*)&sW[row][wc] = v;
        }
        __syncthreads();

#pragma unroll
        for (int k = 0; k < 32; ++k) {
            float a[8], b[8];
            *(float4*)&a[0] = *(const float4*)&sXT[k][ty * 4];
            *(float4*)&a[4] = *(const float4*)&sXT[k][64 + ty * 4];
            *(float4*)&b[0] = *(const float4*)&sW[k][tx * 4];
            *(float4*)&b[4] = *(const float4*)&sW[k][64 + tx * 4];
#pragma unroll
            for (int i = 0; i < 8; ++i)
#pragma unroll
                for (int j = 0; j < 8; ++j)
                    acc[i][j] = fmaf(a[i], b[j], acc[i][j]);
        }
        __syncthreads();
    }

#pragma unroll
    for (int ih = 0; ih < 2; ++ih) {
#pragma unroll
        for (int i = 0; i < 4; ++i) {
            int gr = bm + ih * 64 + ty * 4 + i;
            if (gr >= M) continue;
#pragma unroll
            for (int jh = 0; jh < 2; ++jh) {
                int gc = bn + jh * 64 + tx * 4;
                float4 v = make_float4(acc[ih * 4 + i][jh * 4 + 0],
                                       acc[ih * 4 + i][jh * 4 + 1],
                                       acc[ih * 4 + i][jh * 4 + 2],
                                       acc[ih * 4 + i][jh * 4 + 3]);
                if (gc < 256) {
                    *(float4*)(SRC + (size_t)gr * 256 + gc) = v;
                } else {
                    *(float4*)(DST + (size_t)gr * 256 + (gc - 256)) = v;
                }
            }
        }
    }
}

// ---------- kernel 3: per-src-node edges + fused Gram-Schmidt ----------
// one wave per node; 4 groups of 16 lanes, each group every 4th edge.
// lane l=lane&15 owns channels l*8..l*8+7 of BOTH MLPs.
// 3-deep data pipeline + index prefetched one window earlier: the chain
// idx-load(~200cy) -> row-load(~400cy) is spread over 3 compute windows.
__global__ __launch_bounds__(256) void edge_group_kernel(
    const int* __restrict__ bucket,
    const int* __restrict__ counts,
    const float4* __restrict__ pos4,
    const float* __restrict__ SRC,
    const float* __restrict__ DST,
    const float* __restrict__ w1_0, const float* __restrict__ b1_0,
    const float* __restrict__ w1_1, const float* __restrict__ b1_1,
    const float* __restrict__ w2_0, const float* __restrict__ b2_0,
    const float* __restrict__ w2_1, const float* __restrict__ b2_1,
    float* __restrict__ out, int N)
{
    const int lane = threadIdx.x & 63;
    const int n = blockIdx.x * (blockDim.x >> 6) + (threadIdx.x >> 6);
    if (n >= N) return;
    const int g = lane >> 4;
    const int l = lane & 15;
    const int c8 = l * 8;

    float wd1[8], wo1[8], apb1[8], wd2[8], wo2[8], apb2[8];
    {
        *(float4*)&wd1[0] = *(const float4*)(w1_0 + 256 * 128 + c8);
        *(float4*)&wd1[4] = *(const float4*)(w1_0 + 256 * 128 + c8 + 4);
        *(float4*)&wo1[0] = *(const float4*)(w1_1 + c8);
        *(float4*)&wo1[4] = *(const float4*)(w1_1 + c8 + 4);
        *(float4*)&wd2[0] = *(const float4*)(w2_0 + 256 * 128 + c8);
        *(float4*)&wd2[4] = *(const float4*)(w2_0 + 256 * 128 + c8 + 4);
        *(float4*)&wo2[0] = *(const float4*)(w2_1 + c8);
        *(float4*)&wo2[4] = *(const float4*)(w2_1 + c8 + 4);
        float bb[8], aa[8];
        *(float4*)&bb[0] = *(const float4*)(b1_0 + c8);
        *(float4*)&bb[4] = *(const float4*)(b1_0 + c8 + 4);
        *(float4*)&aa[0] = *(const float4*)(SRC + (size_t)n * 256 + c8);
        *(float4*)&aa[4] = *(const float4*)(SRC + (size_t)n * 256 + c8 + 4);
#pragma unroll
        for (int q = 0; q < 8; ++q) apb1[q] = aa[q] + bb[q];
        *(float4*)&bb[0] = *(const float4*)(b2_0 + c8);
        *(float4*)&bb[4] = *(const float4*)(b2_0 + c8 + 4);
        *(float4*)&aa[0] = *(const float4*)(SRC + (size_t)n * 256 + 128 + c8);
        *(float4*)&aa[4] = *(const float4*)(SRC + (size_t)n * 256 + 128 + c8 + 4);
#pragma unroll
        for (int q = 0; q < 8; ++q) apb2[q] = aa[q] + bb[q];
    }
    const float bias1 = b1_1[0];
    const float bias2 = b2_1[0];

    const float4 p0 = pos4[n];
    const float px = p0.x, py = p0.y, pz = p0.z;

    const int base = n * PAD;
    int cnt = counts[n];
    if (cnt > PAD) cnt = PAD;
    const float inv_cut = 1.0f / 4.5f;

    float a1x = 0.f, a1y = 0.f, a1z = 0.f;
    float a2x = 0.f, a2y = 0.f, a2z = 0.f;

    int i0 = g;
    if (i0 < cnt) {
        // stage A (compute-ready)
        int dA = bucket[base + i0];
        const float* brA = DST + (size_t)dA * 256 + c8;
        float4 A1lo = *(const float4*)brA;
        float4 A1hi = *(const float4*)(brA + 4);
        float4 A2lo = *(const float4*)(brA + 128);
        float4 A2hi = *(const float4*)(brA + 132);
        float4 pA = pos4[dA];

        // stage B (1 window ahead)
        int i1 = i0 + 4;
        int dB = (i1 < cnt) ? bucket[base + i1] : dA;
        const float* brB = DST + (size_t)dB * 256 + c8;
        float4 B1lo = *(const float4*)brB;
        float4 B1hi = *(const float4*)(brB + 4);
        float4 B2lo = *(const float4*)(brB + 128);
        float4 B2hi = *(const float4*)(brB + 132);
        float4 pB = pos4[dB];

        // stage C (2 windows ahead)
        int i2 = i1 + 4;
        int dC = (i2 < cnt) ? bucket[base + i2] : dB;
        const float* brC = DST + (size_t)dC * 256 + c8;
        float4 C1lo = *(const float4*)brC;
        float4 C1hi = *(const float4*)(brC + 4);
        float4 C2lo = *(const float4*)(brC + 128);
        float4 C2hi = *(const float4*)(brC + 132);
        float4 pC = pos4[dC];

        // index for stage D (3 windows ahead)
        int i3 = i2 + 4;
        int dNext = (i3 < cnt) ? bucket[base + i3] : dC;

#pragma unroll 2
        for (;;) {
            // ---- compute edge @ stage A ----
            const float rx = px - pA.x;
            const float ry = py - pA.y;
            const float rz = pz - pA.z;
            const float dist = sqrtf(rx * rx + ry * ry + rz * rz);

            float t1 = 0.f, t2 = 0.f, h;
            h = fmaf(dist, wd1[0], apb1[0] + A1lo.x); t1 = fmaf(fmaxf(h, 0.f), wo1[0], t1);
            h = fmaf(dist, wd1[1], apb1[1] + A1lo.y); t1 = fmaf(fmaxf(h, 0.f), wo1[1], t1);
            h = fmaf(dist, wd1[2], apb1[2] + A1lo.z); t1 = fmaf(fmaxf(h, 0.f), wo1[2], t1);
            h = fmaf(dist, wd1[3], apb1[3] + A1lo.w); t1 = fmaf(fmaxf(h, 0.f), wo1[3], t1);
            h = fmaf(dist, wd1[4], apb1[4] + A1hi.x); t1 = fmaf(fmaxf(h, 0.f), wo1[4], t1);
            h = fmaf(dist, wd1[5], apb1[5] + A1hi.y); t1 = fmaf(fmaxf(h, 0.f), wo1[5], t1);
            h = fmaf(dist, wd1[6], apb1[6] + A1hi.z); t1 = fmaf(fmaxf(h, 0.f), wo1[6], t1);
            h = fmaf(dist, wd1[7], apb1[7] + A1hi.w); t1 = fmaf(fmaxf(h, 0.f), wo1[7], t1);
            h = fmaf(dist, wd2[0], apb2[0] + A2lo.x); t2 = fmaf(fmaxf(h, 0.f), wo2[0], t2);
            h = fmaf(dist, wd2[1], apb2[1] + A2lo.y); t2 = fmaf(fmaxf(h, 0.f), wo2[1], t2);
            h = fmaf(dist, wd2[2], apb2[2] + A2lo.z); t2 = fmaf(fmaxf(h, 0.f), wo2[2], t2);
            h = fmaf(dist, wd2[3], apb2[3] + A2lo.w); t2 = fmaf(fmaxf(h, 0.f), wo2[3], t2);
            h = fmaf(dist, wd2[4], apb2[4] + A2hi.x); t2 = fmaf(fmaxf(h, 0.f), wo2[4], t2);
            h = fmaf(dist, wd2[5], apb2[5] + A2hi.y); t2 = fmaf(fmaxf(h, 0.f), wo2[5], t2);
            h = fmaf(dist, wd2[6], apb2[6] + A2hi.z); t2 = fmaf(fmaxf(h, 0.f), wo2[6], t2);
            h = fmaf(dist, wd2[7], apb2[7] + A2hi.w); t2 = fmaf(fmaxf(h, 0.f), wo2[7], t2);

            t1 += __shfl_xor(t1, 1);  t2 += __shfl_xor(t2, 1);
            t1 += __shfl_xor(t1, 2);  t2 += __shfl_xor(t2, 2);
            t1 += __shfl_xor(t1, 4);  t2 += __shfl_xor(t2, 4);
            t1 += __shfl_xor(t1, 8);  t2 += __shfl_xor(t2, 8);

            const float mes1 = t1 + bias1;
            const float mes2 = t2 + bias2;

            const float dd = dist * inv_cut;
            const float d2 = dd * dd;
            const float d5 = d2 * d2 * dd;
            const float coe = 1.0f - 21.0f * d5 + 35.0f * d5 * dd - 15.0f * d5 * d2;
            const float w = coe / (dist + 1e-12f);
            const float s1 = mes1 * w;
            const float s2 = mes2 * w;

            a1x = fmaf(rx, s1, a1x); a1y = fmaf(ry, s1, a1y); a1z = fmaf(rz, s1, a1z);
            a2x = fmaf(rx, s2, a2x); a2y = fmaf(ry, s2, a2y); a2z = fmaf(rz, s2, a2z);

            if (i1 >= cnt) break;

            // ---- rotate stages: A <- B <- C, issue new C, prefetch index ----
            i0 = i1; i1 = i2; i2 = i3;
            pA = pB; A1lo = B1lo; A1hi = B1hi; A2lo = B2lo; A2hi = B2hi;
            pB = pC; B1lo = C1lo; B1hi = C1hi; B2lo = C2lo; B2hi = C2hi;
            dC = dNext;
            const float* br = DST + (size_t)dC * 256 + c8;
            C1lo = *(const float4*)br;
            C1hi = *(const float4*)(br + 4);
            C2lo = *(const float4*)(br + 128);
            C2hi = *(const float4*)(br + 132);
            pC = pos4[dC];
            i3 = i2 + 4;
            dNext = (i3 < cnt) ? bucket[base + i3] : dC;
        }
    }

    // combine the 4 group partials
    a1x += __shfl_xor(a1x, 16); a1x += __shfl_xor(a1x, 32);
    a1y += __shfl_xor(a1y, 16); a1y += __shfl_xor(a1y, 32);
    a1z += __shfl_xor(a1z, 16); a1z += __shfl_xor(a1z, 32);
    a2x += __shfl_xor(a2x, 16); a2x += __shfl_xor(a2x, 32);
    a2y += __shfl_xor(a2y, 16); a2y += __shfl_xor(a2y, 32);
    a2z += __shfl_xor(a2z, 16); a2z += __shfl_xor(a2z, 32);

    if (lane == 0) {
        float na = sqrtf(a1x * a1x + a1y * a1y + a1z * a1z) + 1e-12f;
        float n1x = a1x / na, n1y = a1y / na, n1z = a1z / na;

        float pr = n1x * a2x + n1y * a2y + n1z * a2z;
        float qx = a2x - pr * n1x, qy = a2y - pr * n1y, qz = a2z - pr * n1z;
        float nq = sqrtf(qx * qx + qy * qy + qz * qz) + 1e-12f;
        float n2x = qx / nq, n2y = qy / nq, n2z = qz / nq;

        float n3x = n1y * n2z - n1z * n2y;
        float n3y = n1z * n2x - n1x * n2z;
        float n3z = n1x * n2y - n1y * n2x;

        float* o = out + (size_t)n * 9;
        o[0] = n1x; o[1] = n1y; o[2] = n1z;
        o[3] = n2x; o[4] = n2y; o[5] = n2z;
        o[6] = n3x; o[7] = n3y; o[8] = n3z;
    }
}

extern "C" void kernel_launch(void* const* d_in, const int* in_sizes, int n_in,
                              void* d_out, int out_size, void* d_ws, size_t ws_size,
                              hipStream_t stream) {
    const float* x    = (const float*)d_in[0];
    const float* pos  = (const float*)d_in[1];
    const int*   eidx = (const int*)d_in[2];
    // d_in[3] = batch (unused)
    const float* w1_0 = (const float*)d_in[4];
    const float* b1_0 = (const float*)d_in[5];
    const float* w1_1 = (const float*)d_in[6];
    const float* b1_1 = (const float*)d_in[7];
    const float* w2_0 = (const float*)d_in[8];
    const float* b2_0 = (const float*)d_in[9];
    const float* w2_1 = (const float*)d_in[10];
    const float* b2_1 = (const float*)d_in[11];

    const int N = in_sizes[0] / 128;
    const int E = in_sizes[2] / 2;

    char* ws = (char*)d_ws;
    float*  W      = (float*)ws;                             // 256 KiB
    float*  SRC    = (float*)(ws + 128 * 512 * 4);           // N*256 f32
    float*  DST    = SRC + (size_t)N * 256;                  // N*256 f32
    float4* pos4   = (float4*)(DST + (size_t)N * 256);       // N float4
    int*    cursor = (int*)(pos4 + N);                       // N (doubles as counts)
    int*    bucket = cursor + N;                             // N*PAD

    const int prep_items = (128 * 512 > N) ? 128 * 512 : N;
    prep_kernel<<<(prep_items + 255) / 256, 256, 0, stream>>>(
        w1_0, w2_0, W, pos, pos4, cursor, N);

    bucket_kernel<<<(E + 255) / 256, 256, 0, stream>>>(eidx, cursor, bucket, E);

    dim3 gg((N + 127) / 128, 4);
    gemm_precompute<<<gg, 256, 0, stream>>>(x, W, SRC, DST, N);

    edge_group_kernel<<<(N + 3) / 4, 256, 0, stream>>>(
        bucket, cursor, pos4, SRC, DST,
        w1_0, b1_0, w1_1, b1_1, w2_0, b2_0, w2_1, b2_1,
        (float*)d_out, N);
}

// Round 12
// 344.668 us; speedup vs baseline: 1.0498x; 1.0498x over previous
//
#include <hip/hip_runtime.h>
#include <cstdint>
#include <cstddef>

#define PAD 64

// ---------- prep: pos->float4 + zero cursor ----------
__global__ void prep_kernel(const float* __restrict__ pos,
                            float4* __restrict__ pos4,
                            int* __restrict__ cursor, int N) {
    int n = blockIdx.x * blockDim.x + threadIdx.x;
    if (n >= N) return;
    pos4[n] = make_float4(pos[3 * n + 0], pos[3 * n + 1], pos[3 * n + 2], 0.f);
    cursor[n] = 0;
}

// ---------- single-pass bucket scatter ----------
__global__ void bucket_kernel(const int* __restrict__ eidx,
                              int* __restrict__ cursor,
                              int* __restrict__ bucket, int E) {
    int e = blockIdx.x * blockDim.x + threadIdx.x;
    if (e >= E) return;
    int s = eidx[e];
    int d = eidx[E + e];
    int r = atomicAdd(&cursor[s], 1);
    if (r < PAD) bucket[(size_t)s * PAD + r] = d;   // P(overflow) ~ 1e-18
}

// ---------- kernel 2: GEMM  C[M,512] = X[M,128] @ Wcombined[128,512] ----------
// W is NOT materialized: each bn-block (bn in {0,128,256,384}) reads entirely
// from one region of w1_0/w2_0:
//   bn=0   -> w1_0 rows 0..127   | bn=128 -> w2_0 rows 0..127
//   bn=256 -> w1_0 rows 128..255 | bn=384 -> w2_0 rows 128..255
// 128x128 tile, 8x8/thread (4+4 split, 64-apart), BK=32, pitch 132.
#define GP 132
__global__ __launch_bounds__(256) void gemm_precompute(
    const float* __restrict__ X,
    const float* __restrict__ w1_0, const float* __restrict__ w2_0,
    float* __restrict__ SRC, float* __restrict__ DST, int M)
{
    __shared__ float sXT[32][GP];   // [k][row]
    __shared__ float sW[32][GP];    // [k][col]

    const int tid = threadIdx.x;
    const int bm = blockIdx.x * 128;
    const int bn = blockIdx.y * 128;
    const int ty = tid >> 4;
    const int tx = tid & 15;

    const int xr = tid >> 3;
    const int xc = (tid & 7) * 4;
    const int wr = tid >> 5;
    const int wc = (tid & 31) * 4;

    // weight source region for this block
    const float* WSRC = (bn & 128) ? w2_0 : w1_0;
    if (bn & 256) WSRC += 128 * 128;

    float acc[8][8];
#pragma unroll
    for (int i = 0; i < 8; ++i)
#pragma unroll
        for (int j = 0; j < 8; ++j) acc[i][j] = 0.f;

    for (int kt = 0; kt < 128; kt += 32) {
#pragma unroll
        for (int q = 0; q < 4; ++q) {
            int row = xr + 32 * q;
            int gr = bm + row;
            float4 v = make_float4(0.f, 0.f, 0.f, 0.f);
            if (gr < M) v = *(const float4*)(X + (size_t)gr * 128 + kt + xc);
            sXT[xc + 0][row] = v.x;
            sXT[xc + 1][row] = v.y;
            sXT[xc + 2][row] = v.z;
            sXT[xc + 3][row] = v.w;
        }
#pragma unroll
        for (int q = 0; q < 4; ++q) {
            int row = wr + 8 * q;
            float4 v = *(const float4*)(WSRC + (size_t)(kt + row) * 128 + wc);
            *(float4*)&sW[row][wc] = v;
        }
        __syncthreads();

#pragma unroll
        for (int k = 0; k < 32; ++k) {
            float a[8], b[8];
            *(float4*)&a[0] = *(const float4*)&sXT[k][ty * 4];
            *(float4*)&a[4] = *(const float4*)&sXT[k][64 + ty * 4];
            *(float4*)&b[0] = *(const float4*)&sW[k][tx * 4];
            *(float4*)&b[4] = *(const float4*)&sW[k][64 + tx * 4];
#pragma unroll
            for (int i = 0; i < 8; ++i)
#pragma unroll
                for (int j = 0; j < 8; ++j)
                    acc[i][j] = fmaf(a[i], b[j], acc[i][j]);
        }
        __syncthreads();
    }

#pragma unroll
    for (int ih = 0; ih < 2; ++ih) {
#pragma unroll
        for (int i = 0; i < 4; ++i) {
            int gr = bm + ih * 64 + ty * 4 + i;
            if (gr >= M) continue;
#pragma unroll
            for (int jh = 0; jh < 2; ++jh) {
                int gc = bn + jh * 64 + tx * 4;
                float4 v = make_float4(acc[ih * 4 + i][jh * 4 + 0],
                                       acc[ih * 4 + i][jh * 4 + 1],
                                       acc[ih * 4 + i][jh * 4 + 2],
                                       acc[ih * 4 + i][jh * 4 + 3]);
                if (gc < 256) {
                    *(float4*)(SRC + (size_t)gr * 256 + gc) = v;
                } else {
                    *(float4*)(DST + (size_t)gr * 256 + (gc - 256)) = v;
                }
            }
        }
    }
}

// ---------- kernel 3: per-src-node edges + fused Gram-Schmidt ----------
// one wave per node; 4 groups of 16 lanes, each group every 4th edge.
// lane l=lane&15 owns channels l*8..l*8+7 of BOTH MLPs.
// 2-deep software pipeline (R10-proven: 52 VGPR, 8 waves/SIMD; 3-deep
// regressed via the 64-VGPR occupancy step — R11).
__global__ __launch_bounds__(256) void edge_group_kernel(
    const int* __restrict__ bucket,
    const int* __restrict__ counts,
    const float4* __restrict__ pos4,
    const float* __restrict__ SRC,
    const float* __restrict__ DST,
    const float* __restrict__ w1_0, const float* __restrict__ b1_0,
    const float* __restrict__ w1_1, const float* __restrict__ b1_1,
    const float* __restrict__ w2_0, const float* __restrict__ b2_0,
    const float* __restrict__ w2_1, const float* __restrict__ b2_1,
    float* __restrict__ out, int N)
{
    const int lane = threadIdx.x & 63;
    const int n = blockIdx.x * (blockDim.x >> 6) + (threadIdx.x >> 6);
    if (n >= N) return;
    const int g = lane >> 4;
    const int l = lane & 15;
    const int c8 = l * 8;

    float wd1[8], wo1[8], apb1[8], wd2[8], wo2[8], apb2[8];
    {
        *(float4*)&wd1[0] = *(const float4*)(w1_0 + 256 * 128 + c8);
        *(float4*)&wd1[4] = *(const float4*)(w1_0 + 256 * 128 + c8 + 4);
        *(float4*)&wo1[0] = *(const float4*)(w1_1 + c8);
        *(float4*)&wo1[4] = *(const float4*)(w1_1 + c8 + 4);
        *(float4*)&wd2[0] = *(const float4*)(w2_0 + 256 * 128 + c8);
        *(float4*)&wd2[4] = *(const float4*)(w2_0 + 256 * 128 + c8 + 4);
        *(float4*)&wo2[0] = *(const float4*)(w2_1 + c8);
        *(float4*)&wo2[4] = *(const float4*)(w2_1 + c8 + 4);
        float bb[8], aa[8];
        *(float4*)&bb[0] = *(const float4*)(b1_0 + c8);
        *(float4*)&bb[4] = *(const float4*)(b1_0 + c8 + 4);
        *(float4*)&aa[0] = *(const float4*)(SRC + (size_t)n * 256 + c8);
        *(float4*)&aa[4] = *(const float4*)(SRC + (size_t)n * 256 + c8 + 4);
#pragma unroll
        for (int q = 0; q < 8; ++q) apb1[q] = aa[q] + bb[q];
        *(float4*)&bb[0] = *(const float4*)(b2_0 + c8);
        *(float4*)&bb[4] = *(const float4*)(b2_0 + c8 + 4);
        *(float4*)&aa[0] = *(const float4*)(SRC + (size_t)n * 256 + 128 + c8);
        *(float4*)&aa[4] = *(const float4*)(SRC + (size_t)n * 256 + 128 + c8 + 4);
#pragma unroll
        for (int q = 0; q < 8; ++q) apb2[q] = aa[q] + bb[q];
    }
    const float bias1 = b1_1[0];
    const float bias2 = b2_1[0];

    const float4 p0 = pos4[n];
    const float px = p0.x, py = p0.y, pz = p0.z;

    const int base = n * PAD;
    int cnt = counts[n];
    if (cnt > PAD) cnt = PAD;
    const float inv_cut = 1.0f / 4.5f;

    float a1x = 0.f, a1y = 0.f, a1z = 0.f;
    float a2x = 0.f, a2y = 0.f, a2z = 0.f;

    int i = g;
    if (i < cnt) {
        int d = bucket[base + i];
        const float* br = DST + (size_t)d * 256 + c8;
        float4 b1lo = *(const float4*)br;
        float4 b1hi = *(const float4*)(br + 4);
        float4 b2lo = *(const float4*)(br + 128);
        float4 b2hi = *(const float4*)(br + 132);
        float4 dp = pos4[d];

        for (;;) {
            const int j = i + 4;
            const bool more = (j < cnt);
            const int dn = more ? bucket[base + j] : d;
            // issue next-edge loads early (pipeline stage 2)
            const float* brn = DST + (size_t)dn * 256 + c8;
            float4 nb1lo = *(const float4*)brn;
            float4 nb1hi = *(const float4*)(brn + 4);
            float4 nb2lo = *(const float4*)(brn + 128);
            float4 nb2hi = *(const float4*)(brn + 132);
            float4 ndp = pos4[dn];

            // compute current edge
            const float rx = px - dp.x;
            const float ry = py - dp.y;
            const float rz = pz - dp.z;
            const float dist = sqrtf(rx * rx + ry * ry + rz * rz);

            float t1 = 0.f, t2 = 0.f, h;
            h = fmaf(dist, wd1[0], apb1[0] + b1lo.x); t1 = fmaf(fmaxf(h, 0.f), wo1[0], t1);
            h = fmaf(dist, wd1[1], apb1[1] + b1lo.y); t1 = fmaf(fmaxf(h, 0.f), wo1[1], t1);
            h = fmaf(dist, wd1[2], apb1[2] + b1lo.z); t1 = fmaf(fmaxf(h, 0.f), wo1[2], t1);
            h = fmaf(dist, wd1[3], apb1[3] + b1lo.w); t1 = fmaf(fmaxf(h, 0.f), wo1[3], t1);
            h = fmaf(dist, wd1[4], apb1[4] + b1hi.x); t1 = fmaf(fmaxf(h, 0.f), wo1[4], t1);
            h = fmaf(dist, wd1[5], apb1[5] + b1hi.y); t1 = fmaf(fmaxf(h, 0.f), wo1[5], t1);
            h = fmaf(dist, wd1[6], apb1[6] + b1hi.z); t1 = fmaf(fmaxf(h, 0.f), wo1[6], t1);
            h = fmaf(dist, wd1[7], apb1[7] + b1hi.w); t1 = fmaf(fmaxf(h, 0.f), wo1[7], t1);
            h = fmaf(dist, wd2[0], apb2[0] + b2lo.x); t2 = fmaf(fmaxf(h, 0.f), wo2[0], t2);
            h = fmaf(dist, wd2[1], apb2[1] + b2lo.y); t2 = fmaf(fmaxf(h, 0.f), wo2[1], t2);
            h = fmaf(dist, wd2[2], apb2[2] + b2lo.z); t2 = fmaf(fmaxf(h, 0.f), wo2[2], t2);
            h = fmaf(dist, wd2[3], apb2[3] + b2lo.w); t2 = fmaf(fmaxf(h, 0.f), wo2[3], t2);
            h = fmaf(dist, wd2[4], apb2[4] + b2hi.x); t2 = fmaf(fmaxf(h, 0.f), wo2[4], t2);
            h = fmaf(dist, wd2[5], apb2[5] + b2hi.y); t2 = fmaf(fmaxf(h, 0.f), wo2[5], t2);
            h = fmaf(dist, wd2[6], apb2[6] + b2hi.z); t2 = fmaf(fmaxf(h, 0.f), wo2[6], t2);
            h = fmaf(dist, wd2[7], apb2[7] + b2hi.w); t2 = fmaf(fmaxf(h, 0.f), wo2[7], t2);

            t1 += __shfl_xor(t1, 1);  t2 += __shfl_xor(t2, 1);
            t1 += __shfl_xor(t1, 2);  t2 += __shfl_xor(t2, 2);
            t1 += __shfl_xor(t1, 4);  t2 += __shfl_xor(t2, 4);
            t1 += __shfl_xor(t1, 8);  t2 += __shfl_xor(t2, 8);

            const float mes1 = t1 + bias1;
            const float mes2 = t2 + bias2;

            const float dd = dist * inv_cut;
            const float d2 = dd * dd;
            const float d5 = d2 * d2 * dd;
            const float coe = 1.0f - 21.0f * d5 + 35.0f * d5 * dd - 15.0f * d5 * d2;
            const float w = coe / (dist + 1e-12f);
            const float s1 = mes1 * w;
            const float s2 = mes2 * w;

            a1x = fmaf(rx, s1, a1x); a1y = fmaf(ry, s1, a1y); a1z = fmaf(rz, s1, a1z);
            a2x = fmaf(rx, s2, a2x); a2y = fmaf(ry, s2, a2y); a2z = fmaf(rz, s2, a2z);

            if (!more) break;
            d = dn; dp = ndp;
            b1lo = nb1lo; b1hi = nb1hi; b2lo = nb2lo; b2hi = nb2hi;
            i = j;
        }
    }

    // combine the 4 group partials
    a1x += __shfl_xor(a1x, 16); a1x += __shfl_xor(a1x, 32);
    a1y += __shfl_xor(a1y, 16); a1y += __shfl_xor(a1y, 32);
    a1z += __shfl_xor(a1z, 16); a1z += __shfl_xor(a1z, 32);
    a2x += __shfl_xor(a2x, 16); a2x += __shfl_xor(a2x, 32);
    a2y += __shfl_xor(a2y, 16); a2y += __shfl_xor(a2y, 32);
    a2z += __shfl_xor(a2z, 16); a2z += __shfl_xor(a2z, 32);

    if (lane == 0) {
        float na = sqrtf(a1x * a1x + a1y * a1y + a1z * a1z) + 1e-12f;
        float n1x = a1x / na, n1y = a1y / na, n1z = a1z / na;

        float pr = n1x * a2x + n1y * a2y + n1z * a2z;
        float qx = a2x - pr * n1x, qy = a2y - pr * n1y, qz = a2z - pr * n1z;
        float nq = sqrtf(qx * qx + qy * qy + qz * qz) + 1e-12f;
        float n2x = qx / nq, n2y = qy / nq, n2z = qz / nq;

        float n3x = n1y * n2z - n1z * n2y;
        float n3y = n1z * n2x - n1x * n2z;
        float n3z = n1x * n2y - n1y * n2x;

        float* o = out + (size_t)n * 9;
        o[0] = n1x; o[1] = n1y; o[2] = n1z;
        o[3] = n2x; o[4] = n2y; o[5] = n2z;
        o[6] = n3x; o[7] = n3y; o[8] = n3z;
    }
}

extern "C" void kernel_launch(void* const* d_in, const int* in_sizes, int n_in,
                              void* d_out, int out_size, void* d_ws, size_t ws_size,
                              hipStream_t stream) {
    const float* x    = (const float*)d_in[0];
    const float* pos  = (const float*)d_in[1];
    const int*   eidx = (const int*)d_in[2];
    // d_in[3] = batch (unused)
    const float* w1_0 = (const float*)d_in[4];
    const float* b1_0 = (const float*)d_in[5];
    const float* w1_1 = (const float*)d_in[6];
    const float* b1_1 = (const float*)d_in[7];
    const float* w2_0 = (const float*)d_in[8];
    const float* b2_0 = (const float*)d_in[9];
    const float* w2_1 = (const float*)d_in[10];
    const float* b2_1 = (const float*)d_in[11];

    const int N = in_sizes[0] / 128;
    const int E = in_sizes[2] / 2;

    char* ws = (char*)d_ws;
    float*  SRC    = (float*)ws;                             // N*256 f32
    float*  DST    = SRC + (size_t)N * 256;                  // N*256 f32
    float4* pos4   = (float4*)(DST + (size_t)N * 256);       // N float4
    int*    cursor = (int*)(pos4 + N);                       // N (doubles as counts)
    int*    bucket = cursor + N;                             // N*PAD

    dim3 gg((N + 127) / 128, 4);
    gemm_precompute<<<gg, 256, 0, stream>>>(x, w1_0, w2_0, SRC, DST, N);

    prep_kernel<<<(N + 255) / 256, 256, 0, stream>>>(pos, pos4, cursor, N);

    bucket_kernel<<<(E + 255) / 256, 256, 0, stream>>>(eidx, cursor, bucket, E);

    edge_group_kernel<<<(N + 3) / 4, 256, 0, stream>>>(
        bucket, cursor, pos4, SRC, DST,
        w1_0, b1_0, w1_1, b1_1, w2_0, b2_0, w2_1, b2_1,
        (float*)d_out, N);
}